// Round 6
// baseline (187.595 us; speedup 1.0000x reference)
//
#include <hip/hip_runtime.h>
#include <hip/hip_bf16.h>
#include <cstdint>
#include <cstddef>

// B=4, S=2048, D=768 single-head causal attention, fp32 I/O.
// Round 11: pv re-tiled from 64x128 (317 TF, staging-bound: 10.9 FLOP/B) to
// 128x128 using the exact gemm_core<128> configuration that measured 611 TF
// in the R0 qkv kernel (256 thr, 32 KB LDS, BK=32 double-buffered prefetch).
// Grid 384 = 16 m-tiles x 6 n-tiles x 4 batches, kend=(mi+1)*128 (covers all
// causal-nonzero k), LPT heavy-first. No atomics. qk256/scores_vt unchanged
// (8-phase core, R10-verified). Measured calibration: 2-phase 128^2 core and
// 8-phase 256^2 core both run ~600 TF; tile intensity, not schedule, is the
// differentiator in this pipeline.

typedef __attribute__((ext_vector_type(8))) short short8;   // 8 x bf16
typedef __attribute__((ext_vector_type(4))) float f32x4;    // MFMA C/D

#define GPTR(p) (const __attribute__((address_space(1))) void*)(p)
#define LPTR(p) (__attribute__((address_space(3))) void*)(p)
#define MFMA16(a8, b8, c) c = __builtin_amdgcn_mfma_f32_16x16x32_bf16(a8, b8, c, 0, 0, 0)

constexpr int CB = 4, CS = 2048, CD = 768;
constexpr int CBS = CB * CS;            // 8192

typedef const __attribute__((address_space(3))) char* lds_cp;

// Inline-asm LDS read: invisible to the compiler's memory model, so it cannot
// insert vmcnt drains against the global_load_lds staging queue.
__device__ __forceinline__ short8 ds_read128(const __hip_bfloat16* p) {
    short8 r;
    lds_cp a = (lds_cp)p;
    asm volatile("ds_read_b128 %0, %1" : "=v"(r) : "v"(a));
    return r;
}

// T1: XCD-aware bijective swizzle (requires nwg % 8 == 0).
__device__ __forceinline__ int xcd_swz(int bid, int nwg) {
    return (bid & 7) * (nwg >> 3) + (bid >> 3);
}

__device__ inline unsigned short f2bf_bits(float v) {
    __hip_bfloat16 h = __float2bfloat16(v);
    unsigned short u;
    __builtin_memcpy(&u, &h, 2);
    return u;
}

__device__ inline ushort4 cvt4(float4 f) {
    ushort4 u;
    u.x = f2bf_bits(f.x); u.y = f2bf_bits(f.y);
    u.z = f2bf_bits(f.z); u.w = f2bf_bits(f.w);
    return u;
}

template <int MI>
__device__ __forceinline__ void zero_acc(f32x4 (&acc)[MI][4]) {
#pragma unroll
    for (int i = 0; i < MI; ++i)
#pragma unroll
        for (int j = 0; j < 4; ++j)
            acc[i][j] = f32x4{0.f, 0.f, 0.f, 0.f};
}

// ---------------------------------------------------------------------------
// single cast dispatch: x -> x16, Wq|Wk|Wv -> w16, and zero rowsum.
// ---------------------------------------------------------------------------
__global__ __launch_bounds__(256) void cvt_all(
    const float4* __restrict__ x,  const float4* __restrict__ wq,
    const float4* __restrict__ wk, const float4* __restrict__ wv,
    ushort4* __restrict__ x16, ushort4* __restrict__ w16,
    float4* __restrict__ rsum4)
{
    constexpr int NX = CBS * CD / 4;        // 1572864
    constexpr int NW = CD * CD / 4;         // 147456
    constexpr int NT = NX + 3 * NW;         // 2015232 (divisible by 256)
    const int i = blockIdx.x * 256 + threadIdx.x;
    if (i < NX) {
        x16[i] = cvt4(x[i]);
    } else if (i < NT) {
        const int j = i - NX;
        if (j < NW)            w16[j] = cvt4(wq[j]);
        else if (j < 2 * NW)   w16[j] = cvt4(wk[j - NW]);
        else                   w16[j] = cvt4(wv[j - 2 * NW]);
    } else {
        const int j = i - NT;               // 0..2047 : zero rowsum (8192 f32)
        rsum4[j] = float4{0.f, 0.f, 0.f, 0.f};
    }
}

// ---------------------------------------------------------------------------
// 256x256 8-phase GEMM core. acc[8][4] += A[m,k]*B[n,k], both K-major (ld K).
// Waves: 2(M) x 4(N); per-wave output 128x64. LDS per operand:
// [2 dbuf][2 half][128 rows][64 k] bf16 (64 KB); total 128 KB.
// Regions (16 KB, staged 1/phase): A-lo, B-b, A-hi, B-a.
// Fragment reads hoisted: {A-lo,B-a,B-b} at K-tile top, A-hi at q2, with
// counted lgkmcnt; q3 reuses B-a regs. Boundary waits: vmcnt(6) per K-tile
// (3 regions of kt+2 in flight); vmcnt(0) at the second-to-last boundary.
// ---------------------------------------------------------------------------
__device__ __forceinline__ void gemm256_core(
    const __hip_bfloat16* __restrict__ A,
    const __hip_bfloat16* __restrict__ B,
    __hip_bfloat16* As, __hip_bfloat16* Bs,
    int m0, int n0, int K, int nkt,
    f32x4 (&acc)[8][4])
{
    const int t   = threadIdx.x;          // 0..511
    const int w   = t >> 6;
    const int l   = t & 63;
    const int lq  = l >> 4;
    const int lm  = l & 15;
    const int wm  = w >> 2;               // M half (0..1)
    const int wn  = w & 3;                // N quarter (0..3)
    const int lm7 = lm & 7;
    const int c0  = (lq ^ lm7) << 3;      // swizzled granule, k-slab 0 (bf16)
    const int c1  = c0 ^ 32;              // k-slab 1

    // staging geometry: thread t covers 16B slots t and 512+t of each region.
    const int rr0   = t >> 3;                         // 0..63
    const int gp8   = (t & 7) << 3;                   // LDS granule (bf16)
    const int g8    = (((t & 7) ^ (rr0 & 7)) << 3);   // pre-swizzled global granule
    const int rowBa = ((rr0 & 32) << 1) | (rr0 & 31); // B-a row-in-half

    const __hip_bfloat16* Aori = A + (size_t)m0 * K;
    const __hip_bfloat16* Bori = B + (size_t)n0 * K;

    auto stage = [&](int reg, int bufT, int kt) {
        const int kc = kt * 64 + g8;
        const __hip_bfloat16* s0;
        __hip_bfloat16* d;
        if (reg == 0) {        // A-lo
            s0 = Aori + (size_t)rr0 * K + kc;
            d  = As + bufT * 16384 + rr0 * 64 + gp8;
        } else if (reg == 2) { // A-hi
            s0 = Aori + (size_t)(64 + rr0) * K + kc;
            d  = As + bufT * 16384 + (64 + rr0) * 64 + gp8;
        } else if (reg == 3) { // B-a
            s0 = Bori + (size_t)rowBa * K + kc;
            d  = Bs + bufT * 16384 + rowBa * 64 + gp8;
        } else {               // B-b
            s0 = Bori + (size_t)(32 + rowBa) * K + kc;
            d  = Bs + bufT * 16384 + (32 + rowBa) * 64 + gp8;
        }
        __builtin_amdgcn_global_load_lds(GPTR(s0), LPTR(d), 16, 0, 0);
        __builtin_amdgcn_global_load_lds(GPTR(s0 + (size_t)128 * K), LPTR(d + 8192), 16, 0, 0);
    };

    // prologue: kt0 {A-lo,B-b,A-hi,B-a} -> buf0; kt1 {A-lo,B-b,A-hi} -> buf1.
    stage(0, 0, 0); stage(1, 0, 0); stage(2, 0, 0); stage(3, 0, 0);
    stage(0, 1, 1); stage(1, 1, 1); stage(2, 1, 1);
    asm volatile("s_waitcnt vmcnt(6)" ::: "memory");   // kt0 complete
    __builtin_amdgcn_s_barrier();

    for (int kt = 0; kt < nkt; ++kt) {
        const int buf = kt & 1;
        const __hip_bfloat16* Ab = As + buf * 16384 + wm * 8192 + lm * 64;
        const __hip_bfloat16* Bb = Bs + buf * 16384 + (wn >> 1) * 8192 + (wn & 1) * 4096 + lm * 64;
        short8 alo[4][2], ahi[4][2], ba[2][2], bb[2][2];

        // ---- K-tile top: issue A-lo(8), B-a(4), B-b(4) reads (in this order;
        // lgkm counts below depend on it). All regions of kt are complete
        // (boundary vmcnt of kt-1), so these are hazard-free.
#pragma unroll
        for (int i = 0; i < 4; ++i) {
            alo[i][0] = ds_read128(&Ab[i * 1024 + c0]);
            alo[i][1] = ds_read128(&Ab[i * 1024 + c1]);
        }
#pragma unroll
        for (int j = 0; j < 2; ++j) {
            ba[j][0] = ds_read128(&Bb[j * 1024 + c0]);
            ba[j][1] = ds_read128(&Bb[j * 1024 + c1]);
        }
#pragma unroll
        for (int j = 0; j < 2; ++j) {
            bb[j][0] = ds_read128(&Bb[(2 + j) * 1024 + c0]);
            bb[j][1] = ds_read128(&Bb[(2 + j) * 1024 + c1]);
        }

        // -------- q0: stage B-a(kt+1) -> buf^1 ; MFMA lo x a
        // needs oldest 12 of 16 reads -> lgkmcnt(4)
        if (kt + 1 < nkt) stage(3, buf ^ 1, kt + 1);
        __builtin_amdgcn_s_barrier();
        asm volatile("s_waitcnt lgkmcnt(4)");
        __builtin_amdgcn_sched_barrier(0);
        __builtin_amdgcn_s_setprio(1);
#pragma unroll
        for (int i = 0; i < 4; ++i)
#pragma unroll
            for (int j = 0; j < 2; ++j) {
                MFMA16(alo[i][0], ba[j][0], acc[i][j]);
                MFMA16(alo[i][1], ba[j][1], acc[i][j]);
            }
        __builtin_amdgcn_s_setprio(0);
        __builtin_amdgcn_s_barrier();   // all waves' A-lo reads done -> q1 stage safe

        // -------- q1: stage A-lo(kt+2) ; MFMA lo x b  (lgkmcnt(0): B-b done)
        if (kt + 2 < nkt) stage(0, buf, kt + 2);
        __builtin_amdgcn_s_barrier();
        asm volatile("s_waitcnt lgkmcnt(0)");
        __builtin_amdgcn_sched_barrier(0);
        __builtin_amdgcn_s_setprio(1);
#pragma unroll
        for (int i = 0; i < 4; ++i)
#pragma unroll
            for (int j = 0; j < 2; ++j) {
                MFMA16(alo[i][0], bb[j][0], acc[i][2 + j]);
                MFMA16(alo[i][1], bb[j][1], acc[i][2 + j]);
            }
        __builtin_amdgcn_s_setprio(0);
        __builtin_amdgcn_s_barrier();   // all waves' B-b reads done -> q2 stage safe

        // -------- q2: read A-hi(8) ; stage B-b(kt+2) ; MFMA hi x b
#pragma unroll
        for (int i = 0; i < 4; ++i) {
            ahi[i][0] = ds_read128(&Ab[(4 + i) * 1024 + c0]);
            ahi[i][1] = ds_read128(&Ab[(4 + i) * 1024 + c1]);
        }
        if (kt + 2 < nkt) stage(1, buf, kt + 2);
        __builtin_amdgcn_s_barrier();
        asm volatile("s_waitcnt lgkmcnt(0)");
        __builtin_amdgcn_sched_barrier(0);
        __builtin_amdgcn_s_setprio(1);
#pragma unroll
        for (int i = 0; i < 4; ++i)
#pragma unroll
            for (int j = 0; j < 2; ++j) {
                MFMA16(ahi[i][0], bb[j][0], acc[4 + i][2 + j]);
                MFMA16(ahi[i][1], bb[j][1], acc[4 + i][2 + j]);
            }
        __builtin_amdgcn_s_setprio(0);
        __builtin_amdgcn_s_barrier();   // all waves' A-hi reads done -> q3 stage safe

        // -------- q3: stage A-hi(kt+2) ; MFMA hi x a (B-a regs reused) ; boundary
        if (kt + 2 < nkt) stage(2, buf, kt + 2);
        __builtin_amdgcn_s_setprio(1);
#pragma unroll
        for (int i = 0; i < 4; ++i)
#pragma unroll
            for (int j = 0; j < 2; ++j) {
                MFMA16(ahi[i][0], ba[j][0], acc[4 + i][j]);
                MFMA16(ahi[i][1], ba[j][1], acc[4 + i][j]);
            }
        __builtin_amdgcn_s_setprio(0);
        if (kt + 2 < nkt) {
            asm volatile("s_waitcnt vmcnt(6)" ::: "memory");   // kt+1 ready
        } else if (kt + 1 < nkt) {
            asm volatile("s_waitcnt vmcnt(0)" ::: "memory");   // drain for last
        }
        __builtin_amdgcn_s_barrier();
    }
}

// ---------------------------------------------------------------------------
// Q/K projections, 256x256 tiles: 192 uniform blocks (32 m-tiles x {Q,K} x 3).
// ---------------------------------------------------------------------------
__global__ __launch_bounds__(512, 2) void qk256_gemm(
    const __hip_bfloat16* __restrict__ x16,
    const __hip_bfloat16* __restrict__ w16,
    __hip_bfloat16* __restrict__ q16,
    __hip_bfloat16* __restrict__ k16)
{
    __shared__ __align__(16) __hip_bfloat16 As[2 * 16384];   // 64 KB
    __shared__ __align__(16) __hip_bfloat16 Bs[2 * 16384];   // 64 KB

    const int id   = xcd_swz(blockIdx.x, 192);   // 0..191
    const int mi   = id / 6;
    const int r    = id % 6;
    const int proj = r / 3;               // 0=Q, 1=K
    const int nj   = r % 3;
    const int m0 = mi * 256, n0 = nj * 256;

    f32x4 acc[8][4];
    zero_acc<8>(acc);
    gemm256_core(x16, w16 + (size_t)proj * CD * CD, As, Bs, m0, n0, CD, CD / 64, acc);

    __hip_bfloat16* C = proj ? k16 : q16;
    const int t = threadIdx.x, w = t >> 6, l = t & 63, lq = l >> 4, lm = l & 15;
    const int wm = w >> 2, wn = w & 3;
#pragma unroll
    for (int i = 0; i < 8; ++i)
#pragma unroll
        for (int j = 0; j < 4; ++j) {
            const int n = n0 + wn * 64 + j * 16 + lm;
#pragma unroll
            for (int r2 = 0; r2 < 4; ++r2) {
                const int m = m0 + wm * 128 + i * 16 + lq * 4 + r2;
                C[(size_t)m * CD + n] = __float2bfloat16(acc[i][j][r2]);
            }
        }
}

// ---------------------------------------------------------------------------
// scores (144 causal 256x256 tiles: E=exp(scale*QK^T), rowsum atomics) and
// V^T projection (96 tiles) fused in one 240-block dispatch (both K=768,
// uniform block duration; V^T is independent of scores).
// ---------------------------------------------------------------------------
__global__ __launch_bounds__(512, 2) void scores_vt_gemm(
    const __hip_bfloat16* __restrict__ q16,
    const __hip_bfloat16* __restrict__ k16,
    const __hip_bfloat16* __restrict__ x16,
    const __hip_bfloat16* __restrict__ w16,
    __hip_bfloat16* __restrict__ sp16,
    __hip_bfloat16* __restrict__ vt16,
    float* __restrict__ rowsum,
    float scale)
{
    __shared__ __align__(16) __hip_bfloat16 As[2 * 16384];   // 64 KB
    __shared__ __align__(16) __hip_bfloat16 Bs[2 * 16384];   // 64 KB

    const int id = xcd_swz(blockIdx.x, 240);     // 0..239
    const __hip_bfloat16 *A, *B;
    int m0, n0, b;
    const bool is_sc = (id < 144);
    if (is_sc) {
        b = id / 36;
        const int tt = id % 36;           // lower-triangle tile index
        int mi = (int)((sqrtf(8.f * tt + 1.f) - 1.f) * 0.5f);
        while ((mi + 1) * (mi + 2) / 2 <= tt) ++mi;
        while (mi * (mi + 1) / 2 > tt) --mi;
        const int nj = tt - mi * (mi + 1) / 2;
        m0 = mi * 256; n0 = nj * 256;
        A = q16 + (size_t)b * CS * CD;
        B = k16 + (size_t)b * CS * CD;
    } else {
        int r = id - 144;
        b = r / 24; r %= 24;
        m0 = (r >> 3) * 256;              // d-tile
        n0 = (r & 7) * 256;               // s-tile
        A = w16 + (size_t)2 * CD * CD;    // Wv
        B = x16 + (size_t)b * CS * CD;
    }

    f32x4 acc[8][4];
    zero_acc<8>(acc);
    gemm256_core(A, B, As, Bs, m0, n0, CD, CD / 64, acc);

    const int t = threadIdx.x, w = t >> 6, l = t & 63, lq = l >> 4, lm = l & 15;
    const int wm = w >> 2, wn = w & 3;

    if (is_sc) {
        __hip_bfloat16* C = sp16 + (size_t)b * CS * CS;
        float* rs = rowsum + (size_t)b * CS;
#pragma unroll
        for (int i = 0; i < 8; ++i) {
            float psum[4] = {0.f, 0.f, 0.f, 0.f};
#pragma unroll
            for (int j = 0; j < 4; ++j) {
                const int n = n0 + wn * 64 + j * 16 + lm;
#pragma unroll
                for (int r2 = 0; r2 < 4; ++r2) {
                    const int m = m0 + wm * 128 + i * 16 + lq * 4 + r2;
                    float e = (n <= m) ? __expf(acc[i][j][r2] * scale) : 0.f;
                    C[(size_t)m * CS + n] = __float2bfloat16(e);
                    psum[r2] += e;
                }
            }
#pragma unroll
            for (int r2 = 0; r2 < 4; ++r2) {
#pragma unroll
                for (int off = 1; off < 16; off <<= 1)
                    psum[r2] += __shfl_xor(psum[r2], off);
                if (lm == 0) {
                    const int m = m0 + wm * 128 + i * 16 + lq * 4 + r2;
                    atomicAdd(&rs[m], psum[r2]);
                }
            }
        }
    } else {
        __hip_bfloat16* C = vt16 + (size_t)b * CD * CS;
#pragma unroll
        for (int i = 0; i < 8; ++i)
#pragma unroll
            for (int j = 0; j < 4; ++j) {
                const int n = n0 + wn * 64 + j * 16 + lm;
#pragma unroll
                for (int r2 = 0; r2 < 4; ++r2) {
                    const int m = m0 + wm * 128 + i * 16 + lq * 4 + r2;
                    C[(size_t)m * CS + n] = __float2bfloat16(acc[i][j][r2]);
                }
            }
    }
}

// ---------------------------------------------------------------------------
// 2-phase GEMM core (pv): acc[MI][4] += A[m,k]*B[n,k], BM x 128 tile, BK=32
// double-buffered prefetch. Same config that measured 611 TF as qkv (R0).
// ---------------------------------------------------------------------------
template <int BM>
__device__ __forceinline__ void gemm_core(
    const __hip_bfloat16* __restrict__ A,
    const __hip_bfloat16* __restrict__ B,
    __hip_bfloat16* As, __hip_bfloat16* Bs,
    int m0, int n0, int K, int kend,
    f32x4 (&acc)[BM / 32][4])
{
    constexpr int AC = BM / 16;
    constexpr int SC = AC + 8;
    constexpr int MI = BM / 32;

    const int t  = threadIdx.x;
    const int w  = t >> 6;
    const int l  = t & 63;
    const int lq = l >> 4;
    const int lm = l & 15;
    const int wm = (w >> 1) * (BM / 2);
    const int wn = (w & 1) * 64;

    const int srow = l >> 2;
    const int scol = (l & 3) * 8;

    auto stage = [&](int buf, int k0) {
#pragma unroll
        for (int ci = 0; ci < SC / 4; ++ci) {
            const int c = ci * 4 + w;
            if (c < AC) {
                __builtin_amdgcn_global_load_lds(
                    GPTR(A + (size_t)(m0 + c * 16 + srow) * K + k0 + scol),
                    LPTR(&As[buf * BM * 32 + c * 512]), 16, 0, 0);
            } else {
                const int c2 = c - AC;
                __builtin_amdgcn_global_load_lds(
                    GPTR(B + (size_t)(n0 + c2 * 16 + srow) * K + k0 + scol),
                    LPTR(&Bs[buf * 128 * 32 + c2 * 512]), 16, 0, 0);
            }
        }
    };

    stage(0, 0);
    asm volatile("s_waitcnt vmcnt(0)" ::: "memory");
    __syncthreads();

    int cur = 0;
    for (int k0 = 0; k0 < kend; k0 += 32) {
        if (k0 + 32 < kend)
            stage(cur ^ 1, k0 + 32);

        short8 af[MI], bf[4];
#pragma unroll
        for (int i = 0; i < MI; ++i)
            af[i] = *(const short8*)&As[cur * BM * 32 + (wm + i * 16 + lm) * 32 + lq * 8];
#pragma unroll
        for (int j = 0; j < 4; ++j)
            bf[j] = *(const short8*)&Bs[cur * 128 * 32 + (wn + j * 16 + lm) * 32 + lq * 8];

#pragma unroll
        for (int i = 0; i < MI; ++i)
#pragma unroll
            for (int j = 0; j < 4; ++j)
                acc[i][j] = __builtin_amdgcn_mfma_f32_16x16x32_bf16(
                    af[i], bf[j], acc[i][j], 0, 0, 0);

        __syncthreads();
        cur ^= 1;
    }
}

// ---------------------------------------------------------------------------
// out[b] = (E[b] @ Vt[b]^T) / rowsum, 128x128 tiles (611-TF-calibrated
// config), kend = m0+128, heavy-first (LPT) ordering.
// Grid: 16 m-tiles x 6 n-tiles x 4 b = 384 blocks.
// ---------------------------------------------------------------------------
__global__ __launch_bounds__(256) void pv_gemm(
    const __hip_bfloat16* __restrict__ sp16,
    const __hip_bfloat16* __restrict__ vt16,
    const float* __restrict__ rowsum,
    float* __restrict__ out)
{
    const int id   = blockIdx.x;        // 0..383
    const int mrev = id / 24;
    int r          = id % 24;
    const int b    = r / 6;
    const int n0   = (r % 6) * 128;
    const int mi   = 15 - mrev;         // heavy (large kend) first
    const int m0   = mi * 128;
    const int kend = m0 + 128;          // covers all causal-nonzero k

    __shared__ __align__(16) __hip_bfloat16 As[2 * 128 * 32];   // 16 KB
    __shared__ __align__(16) __hip_bfloat16 Bs[2 * 128 * 32];   // 16 KB

    const __hip_bfloat16* A = sp16 + (size_t)b * CS * CS;
    const __hip_bfloat16* B = vt16 + (size_t)b * CD * CS;
    float* Co = out + (size_t)b * CS * CD;
    const float* rs = rowsum + (size_t)b * CS;

    f32x4 acc[4][4];
    zero_acc<4>(acc);
    gemm_core<128>(A, B, As, Bs, m0, n0, CS, kend, acc);

    const int t  = threadIdx.x;
    const int w  = t >> 6;
    const int l  = t & 63;
    const int lq = l >> 4;
    const int lm = l & 15;
    const int wm = (w >> 1) * 64;
    const int wn = (w & 1) * 64;

#pragma unroll
    for (int i = 0; i < 4; ++i) {
        float inv[4];
#pragma unroll
        for (int r2 = 0; r2 < 4; ++r2)
            inv[r2] = 1.0f / rs[m0 + wm + i * 16 + lq * 4 + r2];
#pragma unroll
        for (int j = 0; j < 4; ++j) {
            const int n = n0 + wn + j * 16 + lm;
#pragma unroll
            for (int r2 = 0; r2 < 4; ++r2) {
                const int m = m0 + wm + i * 16 + lq * 4 + r2;
                Co[(size_t)m * CD + n] = acc[i][j][r2] * inv[r2];
            }
        }
    }
}

// ---------------------------------------------------------------------------
// Launch
// ---------------------------------------------------------------------------
extern "C" void kernel_launch(void* const* d_in, const int* in_sizes, int n_in,
                              void* d_out, int out_size, void* d_ws, size_t ws_size,
                              hipStream_t stream)
{
    const float* x  = (const float*)d_in[0];
    const float* Wq = (const float*)d_in[1];
    const float* Wk = (const float*)d_in[2];
    const float* Wv = (const float*)d_in[3];
    float* out = (float*)d_out;

    char* ws = (char*)d_ws;
    size_t off = 0;
    auto alloc = [&](size_t bytes) { char* p = ws + off; off += bytes; return p; };

    __hip_bfloat16* x16  = (__hip_bfloat16*)alloc((size_t)CBS * CD * 2);
    __hip_bfloat16* q16  = (__hip_bfloat16*)alloc((size_t)CBS * CD * 2);
    __hip_bfloat16* k16  = (__hip_bfloat16*)alloc((size_t)CBS * CD * 2);
    __hip_bfloat16* vt16 = (__hip_bfloat16*)alloc((size_t)CBS * CD * 2);   // [B][D][S]
    __hip_bfloat16* sp16 = (__hip_bfloat16*)alloc((size_t)CB * CS * CS * 2);
    __hip_bfloat16* w16  = (__hip_bfloat16*)alloc((size_t)3 * CD * CD * 2);
    float*          rsum = (float*)alloc((size_t)CB * CS * sizeof(float));

    constexpr int NCVT_BLK = (CBS * CD + 3 * CD * CD) / 4 / 256 + 8;
    cvt_all<<<NCVT_BLK, 256, 0, stream>>>(
        (const float4*)x, (const float4*)Wq, (const float4*)Wk, (const float4*)Wv,
        (ushort4*)x16, (ushort4*)w16, (float4*)rsum);

    qk256_gemm<<<192, 512, 0, stream>>>(x16, w16, q16, k16);

    scores_vt_gemm<<<240, 512, 0, stream>>>(
        q16, k16, x16, w16, sp16, vt16, rsum, 0.03608439182435161f);

    pv_gemm<<<384, 256, 0, stream>>>(sp16, vt16, rsum, out);
}

// Round 7
// 186.484 us; speedup vs baseline: 1.0060x; 1.0060x over previous
//
#include <hip/hip_runtime.h>
#include <hip/hip_bf16.h>
#include <cstdint>
#include <cstddef>

// B=4, S=2048, D=768 single-head causal attention, fp32 I/O.
// Round 12 (occupancy-first): R6 showed the 2-phase core's per-block rate
// collapses below ~3 blocks/CU (pv 128^2: 384 blocks, occ 8.3%, 47.4 us) and
// the 8-phase 256^2 core is pinned at ~2.5 TF/block at 1 block/CU (qk256: 192
// blocks, ~0.75 blocks/CU, ~40 us). Fix by grid, not schedule:
//  - pv REVERTED to the R3-proven 64x128 / 768-block LPT config (40.6 us
//    measured) + XCD swizzle: each XCD takes 4 consecutive mrev groups, so the
//    6 nj-blocks of one (b,m-tile) share sp16 rows (<=256 KB) and each (b,nj)
//    vt panel (512 KB) recurs 4x in that XCD's L2. Heavy-first preserved.
//  - qk: 2-phase gemm_core<128> at 768 blocks (R0-measured 611 TF on this
//    exact projection shape at 3 blocks/CU) replaces the 192-block qk256.
//  - scores_vt: unchanged 8-phase 240-block dispatch (best measured).

typedef __attribute__((ext_vector_type(8))) short short8;   // 8 x bf16
typedef __attribute__((ext_vector_type(4))) float f32x4;    // MFMA C/D

#define GPTR(p) (const __attribute__((address_space(1))) void*)(p)
#define LPTR(p) (__attribute__((address_space(3))) void*)(p)
#define MFMA16(a8, b8, c) c = __builtin_amdgcn_mfma_f32_16x16x32_bf16(a8, b8, c, 0, 0, 0)

constexpr int CB = 4, CS = 2048, CD = 768;
constexpr int CBS = CB * CS;            // 8192

typedef const __attribute__((address_space(3))) char* lds_cp;

// Inline-asm LDS read: invisible to the compiler's memory model, so it cannot
// insert vmcnt drains against the global_load_lds staging queue.
__device__ __forceinline__ short8 ds_read128(const __hip_bfloat16* p) {
    short8 r;
    lds_cp a = (lds_cp)p;
    asm volatile("ds_read_b128 %0, %1" : "=v"(r) : "v"(a));
    return r;
}

// T1: XCD-aware bijective swizzle (requires nwg % 8 == 0).
__device__ __forceinline__ int xcd_swz(int bid, int nwg) {
    return (bid & 7) * (nwg >> 3) + (bid >> 3);
}

__device__ inline unsigned short f2bf_bits(float v) {
    __hip_bfloat16 h = __float2bfloat16(v);
    unsigned short u;
    __builtin_memcpy(&u, &h, 2);
    return u;
}

__device__ inline ushort4 cvt4(float4 f) {
    ushort4 u;
    u.x = f2bf_bits(f.x); u.y = f2bf_bits(f.y);
    u.z = f2bf_bits(f.z); u.w = f2bf_bits(f.w);
    return u;
}

template <int MI>
__device__ __forceinline__ void zero_acc(f32x4 (&acc)[MI][4]) {
#pragma unroll
    for (int i = 0; i < MI; ++i)
#pragma unroll
        for (int j = 0; j < 4; ++j)
            acc[i][j] = f32x4{0.f, 0.f, 0.f, 0.f};
}

// ---------------------------------------------------------------------------
// single cast dispatch: x -> x16, Wq|Wk|Wv -> w16, and zero rowsum.
// ---------------------------------------------------------------------------
__global__ __launch_bounds__(256) void cvt_all(
    const float4* __restrict__ x,  const float4* __restrict__ wq,
    const float4* __restrict__ wk, const float4* __restrict__ wv,
    ushort4* __restrict__ x16, ushort4* __restrict__ w16,
    float4* __restrict__ rsum4)
{
    constexpr int NX = CBS * CD / 4;        // 1572864
    constexpr int NW = CD * CD / 4;         // 147456
    constexpr int NT = NX + 3 * NW;         // 2015232 (divisible by 256)
    const int i = blockIdx.x * 256 + threadIdx.x;
    if (i < NX) {
        x16[i] = cvt4(x[i]);
    } else if (i < NT) {
        const int j = i - NX;
        if (j < NW)            w16[j] = cvt4(wq[j]);
        else if (j < 2 * NW)   w16[j] = cvt4(wk[j - NW]);
        else                   w16[j] = cvt4(wv[j - 2 * NW]);
    } else {
        const int j = i - NT;               // 0..2047 : zero rowsum (8192 f32)
        rsum4[j] = float4{0.f, 0.f, 0.f, 0.f};
    }
}

// ---------------------------------------------------------------------------
// 256x256 8-phase GEMM core (scores_vt). acc[8][4] += A[m,k]*B[n,k].
// Fragment reads hoisted with counted lgkmcnt; q3 reuses B-a regs; counted
// vmcnt(6) at K-tile boundaries. (R10-verified)
// ---------------------------------------------------------------------------
__device__ __forceinline__ void gemm256_core(
    const __hip_bfloat16* __restrict__ A,
    const __hip_bfloat16* __restrict__ B,
    __hip_bfloat16* As, __hip_bfloat16* Bs,
    int m0, int n0, int K, int nkt,
    f32x4 (&acc)[8][4])
{
    const int t   = threadIdx.x;          // 0..511
    const int w   = t >> 6;
    const int l   = t & 63;
    const int lq  = l >> 4;
    const int lm  = l & 15;
    const int wm  = w >> 2;               // M half (0..1)
    const int wn  = w & 3;                // N quarter (0..3)
    const int lm7 = lm & 7;
    const int c0  = (lq ^ lm7) << 3;      // swizzled granule, k-slab 0 (bf16)
    const int c1  = c0 ^ 32;              // k-slab 1

    // staging geometry: thread t covers 16B slots t and 512+t of each region.
    const int rr0   = t >> 3;                         // 0..63
    const int gp8   = (t & 7) << 3;                   // LDS granule (bf16)
    const int g8    = (((t & 7) ^ (rr0 & 7)) << 3);   // pre-swizzled global granule
    const int rowBa = ((rr0 & 32) << 1) | (rr0 & 31); // B-a row-in-half

    const __hip_bfloat16* Aori = A + (size_t)m0 * K;
    const __hip_bfloat16* Bori = B + (size_t)n0 * K;

    auto stage = [&](int reg, int bufT, int kt) {
        const int kc = kt * 64 + g8;
        const __hip_bfloat16* s0;
        __hip_bfloat16* d;
        if (reg == 0) {        // A-lo
            s0 = Aori + (size_t)rr0 * K + kc;
            d  = As + bufT * 16384 + rr0 * 64 + gp8;
        } else if (reg == 2) { // A-hi
            s0 = Aori + (size_t)(64 + rr0) * K + kc;
            d  = As + bufT * 16384 + (64 + rr0) * 64 + gp8;
        } else if (reg == 3) { // B-a
            s0 = Bori + (size_t)rowBa * K + kc;
            d  = Bs + bufT * 16384 + rowBa * 64 + gp8;
        } else {               // B-b
            s0 = Bori + (size_t)(32 + rowBa) * K + kc;
            d  = Bs + bufT * 16384 + (32 + rowBa) * 64 + gp8;
        }
        __builtin_amdgcn_global_load_lds(GPTR(s0), LPTR(d), 16, 0, 0);
        __builtin_amdgcn_global_load_lds(GPTR(s0 + (size_t)128 * K), LPTR(d + 8192), 16, 0, 0);
    };

    // prologue: kt0 {A-lo,B-b,A-hi,B-a} -> buf0; kt1 {A-lo,B-b,A-hi} -> buf1.
    stage(0, 0, 0); stage(1, 0, 0); stage(2, 0, 0); stage(3, 0, 0);
    stage(0, 1, 1); stage(1, 1, 1); stage(2, 1, 1);
    asm volatile("s_waitcnt vmcnt(6)" ::: "memory");   // kt0 complete
    __builtin_amdgcn_s_barrier();

    for (int kt = 0; kt < nkt; ++kt) {
        const int buf = kt & 1;
        const __hip_bfloat16* Ab = As + buf * 16384 + wm * 8192 + lm * 64;
        const __hip_bfloat16* Bb = Bs + buf * 16384 + (wn >> 1) * 8192 + (wn & 1) * 4096 + lm * 64;
        short8 alo[4][2], ahi[4][2], ba[2][2], bb[2][2];

        // ---- K-tile top: issue A-lo(8), B-a(4), B-b(4) reads.
#pragma unroll
        for (int i = 0; i < 4; ++i) {
            alo[i][0] = ds_read128(&Ab[i * 1024 + c0]);
            alo[i][1] = ds_read128(&Ab[i * 1024 + c1]);
        }
#pragma unroll
        for (int j = 0; j < 2; ++j) {
            ba[j][0] = ds_read128(&Bb[j * 1024 + c0]);
            ba[j][1] = ds_read128(&Bb[j * 1024 + c1]);
        }
#pragma unroll
        for (int j = 0; j < 2; ++j) {
            bb[j][0] = ds_read128(&Bb[(2 + j) * 1024 + c0]);
            bb[j][1] = ds_read128(&Bb[(2 + j) * 1024 + c1]);
        }

        // -------- q0: stage B-a(kt+1) -> buf^1 ; MFMA lo x a
        if (kt + 1 < nkt) stage(3, buf ^ 1, kt + 1);
        __builtin_amdgcn_s_barrier();
        asm volatile("s_waitcnt lgkmcnt(4)");
        __builtin_amdgcn_sched_barrier(0);
        __builtin_amdgcn_s_setprio(1);
#pragma unroll
        for (int i = 0; i < 4; ++i)
#pragma unroll
            for (int j = 0; j < 2; ++j) {
                MFMA16(alo[i][0], ba[j][0], acc[i][j]);
                MFMA16(alo[i][1], ba[j][1], acc[i][j]);
            }
        __builtin_amdgcn_s_setprio(0);
        __builtin_amdgcn_s_barrier();

        // -------- q1: stage A-lo(kt+2) ; MFMA lo x b
        if (kt + 2 < nkt) stage(0, buf, kt + 2);
        __builtin_amdgcn_s_barrier();
        asm volatile("s_waitcnt lgkmcnt(0)");
        __builtin_amdgcn_sched_barrier(0);
        __builtin_amdgcn_s_setprio(1);
#pragma unroll
        for (int i = 0; i < 4; ++i)
#pragma unroll
            for (int j = 0; j < 2; ++j) {
                MFMA16(alo[i][0], bb[j][0], acc[i][2 + j]);
                MFMA16(alo[i][1], bb[j][1], acc[i][2 + j]);
            }
        __builtin_amdgcn_s_setprio(0);
        __builtin_amdgcn_s_barrier();

        // -------- q2: read A-hi(8) ; stage B-b(kt+2) ; MFMA hi x b
#pragma unroll
        for (int i = 0; i < 4; ++i) {
            ahi[i][0] = ds_read128(&Ab[(4 + i) * 1024 + c0]);
            ahi[i][1] = ds_read128(&Ab[(4 + i) * 1024 + c1]);
        }
        if (kt + 2 < nkt) stage(1, buf, kt + 2);
        __builtin_amdgcn_s_barrier();
        asm volatile("s_waitcnt lgkmcnt(0)");
        __builtin_amdgcn_sched_barrier(0);
        __builtin_amdgcn_s_setprio(1);
#pragma unroll
        for (int i = 0; i < 4; ++i)
#pragma unroll
            for (int j = 0; j < 2; ++j) {
                MFMA16(ahi[i][0], bb[j][0], acc[4 + i][2 + j]);
                MFMA16(ahi[i][1], bb[j][1], acc[4 + i][2 + j]);
            }
        __builtin_amdgcn_s_setprio(0);
        __builtin_amdgcn_s_barrier();

        // -------- q3: stage A-hi(kt+2) ; MFMA hi x a (B-a regs reused) ; boundary
        if (kt + 2 < nkt) stage(2, buf, kt + 2);
        __builtin_amdgcn_s_setprio(1);
#pragma unroll
        for (int i = 0; i < 4; ++i)
#pragma unroll
            for (int j = 0; j < 2; ++j) {
                MFMA16(ahi[i][0], ba[j][0], acc[4 + i][j]);
                MFMA16(ahi[i][1], ba[j][1], acc[4 + i][j]);
            }
        __builtin_amdgcn_s_setprio(0);
        if (kt + 2 < nkt) {
            asm volatile("s_waitcnt vmcnt(6)" ::: "memory");   // kt+1 ready
        } else if (kt + 1 < nkt) {
            asm volatile("s_waitcnt vmcnt(0)" ::: "memory");   // drain for last
        }
        __builtin_amdgcn_s_barrier();
    }
}

// ---------------------------------------------------------------------------
// scores (144 causal 256x256 tiles: E=exp(scale*QK^T), rowsum atomics) and
// V^T projection (96 tiles) fused in one 240-block dispatch.
// ---------------------------------------------------------------------------
__global__ __launch_bounds__(512, 2) void scores_vt_gemm(
    const __hip_bfloat16* __restrict__ q16,
    const __hip_bfloat16* __restrict__ k16,
    const __hip_bfloat16* __restrict__ x16,
    const __hip_bfloat16* __restrict__ w16,
    __hip_bfloat16* __restrict__ sp16,
    __hip_bfloat16* __restrict__ vt16,
    float* __restrict__ rowsum,
    float scale)
{
    __shared__ __align__(16) __hip_bfloat16 As[2 * 16384];   // 64 KB
    __shared__ __align__(16) __hip_bfloat16 Bs[2 * 16384];   // 64 KB

    const int id = xcd_swz(blockIdx.x, 240);     // 0..239
    const __hip_bfloat16 *A, *B;
    int m0, n0, b;
    const bool is_sc = (id < 144);
    if (is_sc) {
        b = id / 36;
        const int tt = id % 36;           // lower-triangle tile index
        int mi = (int)((sqrtf(8.f * tt + 1.f) - 1.f) * 0.5f);
        while ((mi + 1) * (mi + 2) / 2 <= tt) ++mi;
        while (mi * (mi + 1) / 2 > tt) --mi;
        const int nj = tt - mi * (mi + 1) / 2;
        m0 = mi * 256; n0 = nj * 256;
        A = q16 + (size_t)b * CS * CD;
        B = k16 + (size_t)b * CS * CD;
    } else {
        int r = id - 144;
        b = r / 24; r %= 24;
        m0 = (r >> 3) * 256;              // d-tile
        n0 = (r & 7) * 256;               // s-tile
        A = w16 + (size_t)2 * CD * CD;    // Wv
        B = x16 + (size_t)b * CS * CD;
    }

    f32x4 acc[8][4];
    zero_acc<8>(acc);
    gemm256_core(A, B, As, Bs, m0, n0, CD, CD / 64, acc);

    const int t = threadIdx.x, w = t >> 6, l = t & 63, lq = l >> 4, lm = l & 15;
    const int wm = w >> 2, wn = w & 3;

    if (is_sc) {
        __hip_bfloat16* C = sp16 + (size_t)b * CS * CS;
        float* rs = rowsum + (size_t)b * CS;
#pragma unroll
        for (int i = 0; i < 8; ++i) {
            float psum[4] = {0.f, 0.f, 0.f, 0.f};
#pragma unroll
            for (int j = 0; j < 4; ++j) {
                const int n = n0 + wn * 64 + j * 16 + lm;
#pragma unroll
                for (int r2 = 0; r2 < 4; ++r2) {
                    const int m = m0 + wm * 128 + i * 16 + lq * 4 + r2;
                    float e = (n <= m) ? __expf(acc[i][j][r2] * scale) : 0.f;
                    C[(size_t)m * CS + n] = __float2bfloat16(e);
                    psum[r2] += e;
                }
            }
#pragma unroll
            for (int r2 = 0; r2 < 4; ++r2) {
#pragma unroll
                for (int off = 1; off < 16; off <<= 1)
                    psum[r2] += __shfl_xor(psum[r2], off);
                if (lm == 0) {
                    const int m = m0 + wm * 128 + i * 16 + lq * 4 + r2;
                    atomicAdd(&rs[m], psum[r2]);
                }
            }
        }
    } else {
        __hip_bfloat16* C = vt16 + (size_t)b * CD * CS;
#pragma unroll
        for (int i = 0; i < 8; ++i)
#pragma unroll
            for (int j = 0; j < 4; ++j) {
                const int n = n0 + wn * 64 + j * 16 + lm;
#pragma unroll
                for (int r2 = 0; r2 < 4; ++r2) {
                    const int m = m0 + wm * 128 + i * 16 + lq * 4 + r2;
                    C[(size_t)m * CS + n] = __float2bfloat16(acc[i][j][r2]);
                }
            }
    }
}

// ---------------------------------------------------------------------------
// 2-phase GEMM core: acc[MI][4] += A[m,k]*B[n,k], BM x 128 tile, BK=32
// double-buffered prefetch. R0-proven at 611 TF aggregate (>=3 blocks/CU).
// ---------------------------------------------------------------------------
template <int BM>
__device__ __forceinline__ void gemm_core(
    const __hip_bfloat16* __restrict__ A,
    const __hip_bfloat16* __restrict__ B,
    __hip_bfloat16* As, __hip_bfloat16* Bs,
    int m0, int n0, int K, int kend,
    f32x4 (&acc)[BM / 32][4])
{
    constexpr int AC = BM / 16;
    constexpr int SC = AC + 8;
    constexpr int MI = BM / 32;

    const int t  = threadIdx.x;
    const int w  = t >> 6;
    const int l  = t & 63;
    const int lq = l >> 4;
    const int lm = l & 15;
    const int wm = (w >> 1) * (BM / 2);
    const int wn = (w & 1) * 64;

    const int srow = l >> 2;
    const int scol = (l & 3) * 8;

    auto stage = [&](int buf, int k0) {
#pragma unroll
        for (int ci = 0; ci < SC / 4; ++ci) {
            const int c = ci * 4 + w;
            if (c < AC) {
                __builtin_amdgcn_global_load_lds(
                    GPTR(A + (size_t)(m0 + c * 16 + srow) * K + k0 + scol),
                    LPTR(&As[buf * BM * 32 + c * 512]), 16, 0, 0);
            } else {
                const int c2 = c - AC;
                __builtin_amdgcn_global_load_lds(
                    GPTR(B + (size_t)(n0 + c2 * 16 + srow) * K + k0 + scol),
                    LPTR(&Bs[buf * 128 * 32 + c2 * 512]), 16, 0, 0);
            }
        }
    };

    stage(0, 0);
    asm volatile("s_waitcnt vmcnt(0)" ::: "memory");
    __syncthreads();

    int cur = 0;
    for (int k0 = 0; k0 < kend; k0 += 32) {
        if (k0 + 32 < kend)
            stage(cur ^ 1, k0 + 32);

        short8 af[MI], bf[4];
#pragma unroll
        for (int i = 0; i < MI; ++i)
            af[i] = *(const short8*)&As[cur * BM * 32 + (wm + i * 16 + lm) * 32 + lq * 8];
#pragma unroll
        for (int j = 0; j < 4; ++j)
            bf[j] = *(const short8*)&Bs[cur * 128 * 32 + (wn + j * 16 + lm) * 32 + lq * 8];

#pragma unroll
        for (int i = 0; i < MI; ++i)
#pragma unroll
            for (int j = 0; j < 4; ++j)
                acc[i][j] = __builtin_amdgcn_mfma_f32_16x16x32_bf16(
                    af[i], bf[j], acc[i][j], 0, 0, 0);

        __syncthreads();
        cur ^= 1;
    }
}

// ---------------------------------------------------------------------------
// Q/K projections, 128x128 tiles, 768 blocks (Q: 0..383, K: 384..767),
// 3 blocks/CU. XCD swizzle: each XCD gets contiguous tile runs sharing x
// row-panels (196 KB) and W col-panels (196 KB) in its L2.
// ---------------------------------------------------------------------------
__global__ __launch_bounds__(256) void qk_gemm(
    const __hip_bfloat16* __restrict__ x16,
    const __hip_bfloat16* __restrict__ w16,
    __hip_bfloat16* __restrict__ q16,
    __hip_bfloat16* __restrict__ k16)
{
    __shared__ __align__(16) __hip_bfloat16 As[2 * 128 * 32];   // 16 KB
    __shared__ __align__(16) __hip_bfloat16 Bs[2 * 128 * 32];   // 16 KB

    const int id   = xcd_swz(blockIdx.x, 768);   // 0..767
    const int proj = id / 384;            // 0=Q, 1=K
    const int r    = id % 384;
    const int n0   = (r % 6) * 128;
    const int m0   = (r / 6) * 128;

    f32x4 acc[4][4];
    zero_acc<4>(acc);
    gemm_core<128>(x16, w16 + (size_t)proj * CD * CD, As, Bs, m0, n0, CD, CD, acc);

    __hip_bfloat16* C = proj ? k16 : q16;
    const int t  = threadIdx.x;
    const int w  = t >> 6;
    const int l  = t & 63;
    const int lq = l >> 4;
    const int lm = l & 15;
    const int wm = (w >> 1) * 64;
    const int wn = (w & 1) * 64;
#pragma unroll
    for (int i = 0; i < 4; ++i)
#pragma unroll
        for (int j = 0; j < 4; ++j) {
            const int n = n0 + wn + j * 16 + lm;
#pragma unroll
            for (int r2 = 0; r2 < 4; ++r2) {
                const int m = m0 + wm + i * 16 + lq * 4 + r2;
                C[(size_t)m * CD + n] = __float2bfloat16(acc[i][j][r2]);
            }
        }
}

// ---------------------------------------------------------------------------
// out[b] = (E[b] @ Vt[b]^T) / rowsum, 64x128 tiles, kend = m0+64,
// heavy-first (LPT) + XCD swizzle: XCD k gets mrev 4k..4k+3 (heavy-first
// within XCD); the 6 nj-blocks of one (b,m-tile) share sp16 rows in L2 and
// each (b,nj) vt panel (512 KB) recurs 4x.  (R3-verified core config)
// ---------------------------------------------------------------------------
__global__ __launch_bounds__(256) void pv_gemm(
    const __hip_bfloat16* __restrict__ sp16,
    const __hip_bfloat16* __restrict__ vt16,
    const float* __restrict__ rowsum,
    float* __restrict__ out)
{
    const int id   = xcd_swz(blockIdx.x, 768);  // 0..767
    const int mrev = id / 24;
    int r          = id % 24;
    const int b    = r / 6;
    const int n0   = (r % 6) * 128;
    const int mi   = 31 - mrev;
    const int m0   = mi * 64;
    const int kend = m0 + 64;

    __shared__ __align__(16) __hip_bfloat16 As[2 * 64 * 32];    // 8 KB
    __shared__ __align__(16) __hip_bfloat16 Bs[2 * 128 * 32];   // 16 KB

    const __hip_bfloat16* A = sp16 + (size_t)b * CS * CS;
    const __hip_bfloat16* B = vt16 + (size_t)b * CD * CS;
    float* Co = out + (size_t)b * CS * CD;
    const float* rs = rowsum + (size_t)b * CS;

    f32x4 acc[2][4];
    zero_acc<2>(acc);
    gemm_core<64>(A, B, As, Bs, m0, n0, CS, kend, acc);

    const int t  = threadIdx.x;
    const int w  = t >> 6;
    const int l  = t & 63;
    const int lq = l >> 4;
    const int lm = l & 15;
    const int wm = (w >> 1) * 32;
    const int wn = (w & 1) * 64;

#pragma unroll
    for (int i = 0; i < 2; ++i) {
        float inv[4];
#pragma unroll
        for (int r2 = 0; r2 < 4; ++r2)
            inv[r2] = 1.0f / rs[m0 + wm + i * 16 + lq * 4 + r2];
#pragma unroll
        for (int j = 0; j < 4; ++j) {
            const int n = n0 + wn + j * 16 + lm;
#pragma unroll
            for (int r2 = 0; r2 < 4; ++r2) {
                const int m = m0 + wm + i * 16 + lq * 4 + r2;
                Co[(size_t)m * CD + n] = acc[i][j][r2] * inv[r2];
            }
        }
    }
}

// ---------------------------------------------------------------------------
// Launch
// ---------------------------------------------------------------------------
extern "C" void kernel_launch(void* const* d_in, const int* in_sizes, int n_in,
                              void* d_out, int out_size, void* d_ws, size_t ws_size,
                              hipStream_t stream)
{
    const float* x  = (const float*)d_in[0];
    const float* Wq = (const float*)d_in[1];
    const float* Wk = (const float*)d_in[2];
    const float* Wv = (const float*)d_in[3];
    float* out = (float*)d_out;

    char* ws = (char*)d_ws;
    size_t off = 0;
    auto alloc = [&](size_t bytes) { char* p = ws + off; off += bytes; return p; };

    __hip_bfloat16* x16  = (__hip_bfloat16*)alloc((size_t)CBS * CD * 2);
    __hip_bfloat16* q16  = (__hip_bfloat16*)alloc((size_t)CBS * CD * 2);
    __hip_bfloat16* k16  = (__hip_bfloat16*)alloc((size_t)CBS * CD * 2);
    __hip_bfloat16* vt16 = (__hip_bfloat16*)alloc((size_t)CBS * CD * 2);   // [B][D][S]
    __hip_bfloat16* sp16 = (__hip_bfloat16*)alloc((size_t)CB * CS * CS * 2);
    __hip_bfloat16* w16  = (__hip_bfloat16*)alloc((size_t)3 * CD * CD * 2);
    float*          rsum = (float*)alloc((size_t)CB * CS * sizeof(float));

    constexpr int NCVT_BLK = (CBS * CD + 3 * CD * CD) / 4 / 256 + 8;
    cvt_all<<<NCVT_BLK, 256, 0, stream>>>(
        (const float4*)x, (const float4*)Wq, (const float4*)Wk, (const float4*)Wv,
        (ushort4*)x16, (ushort4*)w16, (float4*)rsum);

    qk_gemm<<<768, 256, 0, stream>>>(x16, w16, q16, k16);

    scores_vt_gemm<<<240, 512, 0, stream>>>(
        q16, k16, x16, w16, sp16, vt16, rsum, 0.03608439182435161f);

    pv_gemm<<<768, 256, 0, stream>>>(sp16, vt16, rsum, out);
}

// Round 8
// 174.683 us; speedup vs baseline: 1.0739x; 1.0676x over previous
//
#include <hip/hip_runtime.h>
#include <hip/hip_bf16.h>
#include <cstdint>
#include <cstddef>

// B=4, S=2048, D=768 single-head causal attention, fp32 I/O.
// Round 13: pv fixed two ways.
//  (1) XCD swizzle REMOVED (R7: it gave XCD0 the 4 heaviest mrev groups and
//      XCD7 the lightest -> ~8:1 inter-XCD imbalance, 40.6 -> 48.8 us, even
//      though FETCH dropped 57->36 GB). Plain blockIdx LPT restored.
//  (2) Core upgraded to BK=64 double-buffered prefetch: stage BOTH 32-slabs
//      (12 load-ops), 16 MFMA, ONE __syncthreads+vmcnt-drain per 64
//      K-elements. R0->R1 analysis showed the drain EVENT (not staging bytes)
//      is the per-iteration cost; my R1 prefetch loop halved BK and doubled
//      the event rate. This restores R0's event rate AND keeps the prefetch
//      overlap. LDS 24->48 KB, still exactly 3 blocks/CU at 768 blocks.
// qk (768-block 2-phase BK=32) and scores_vt (240-block 8-phase) unchanged
// from R7; cvt unchanged.

typedef __attribute__((ext_vector_type(8))) short short8;   // 8 x bf16
typedef __attribute__((ext_vector_type(4))) float f32x4;    // MFMA C/D

#define GPTR(p) (const __attribute__((address_space(1))) void*)(p)
#define LPTR(p) (__attribute__((address_space(3))) void*)(p)
#define MFMA16(a8, b8, c) c = __builtin_amdgcn_mfma_f32_16x16x32_bf16(a8, b8, c, 0, 0, 0)

constexpr int CB = 4, CS = 2048, CD = 768;
constexpr int CBS = CB * CS;            // 8192

typedef const __attribute__((address_space(3))) char* lds_cp;

// Inline-asm LDS read: invisible to the compiler's memory model, so it cannot
// insert vmcnt drains against the global_load_lds staging queue.
__device__ __forceinline__ short8 ds_read128(const __hip_bfloat16* p) {
    short8 r;
    lds_cp a = (lds_cp)p;
    asm volatile("ds_read_b128 %0, %1" : "=v"(r) : "v"(a));
    return r;
}

// T1: XCD-aware bijective swizzle (requires nwg % 8 == 0). Used only where
// block durations are uniform (qk, scores_vt) -- NOT on LPT grids (R7 lesson).
__device__ __forceinline__ int xcd_swz(int bid, int nwg) {
    return (bid & 7) * (nwg >> 3) + (bid >> 3);
}

__device__ inline unsigned short f2bf_bits(float v) {
    __hip_bfloat16 h = __float2bfloat16(v);
    unsigned short u;
    __builtin_memcpy(&u, &h, 2);
    return u;
}

__device__ inline ushort4 cvt4(float4 f) {
    ushort4 u;
    u.x = f2bf_bits(f.x); u.y = f2bf_bits(f.y);
    u.z = f2bf_bits(f.z); u.w = f2bf_bits(f.w);
    return u;
}

template <int MI>
__device__ __forceinline__ void zero_acc(f32x4 (&acc)[MI][4]) {
#pragma unroll
    for (int i = 0; i < MI; ++i)
#pragma unroll
        for (int j = 0; j < 4; ++j)
            acc[i][j] = f32x4{0.f, 0.f, 0.f, 0.f};
}

// ---------------------------------------------------------------------------
// single cast dispatch: x -> x16, Wq|Wk|Wv -> w16, and zero rowsum.
// ---------------------------------------------------------------------------
__global__ __launch_bounds__(256) void cvt_all(
    const float4* __restrict__ x,  const float4* __restrict__ wq,
    const float4* __restrict__ wk, const float4* __restrict__ wv,
    ushort4* __restrict__ x16, ushort4* __restrict__ w16,
    float4* __restrict__ rsum4)
{
    constexpr int NX = CBS * CD / 4;        // 1572864
    constexpr int NW = CD * CD / 4;         // 147456
    constexpr int NT = NX + 3 * NW;         // 2015232 (divisible by 256)
    const int i = blockIdx.x * 256 + threadIdx.x;
    if (i < NX) {
        x16[i] = cvt4(x[i]);
    } else if (i < NT) {
        const int j = i - NX;
        if (j < NW)            w16[j] = cvt4(wq[j]);
        else if (j < 2 * NW)   w16[j] = cvt4(wk[j - NW]);
        else                   w16[j] = cvt4(wv[j - 2 * NW]);
    } else {
        const int j = i - NT;               // 0..2047 : zero rowsum (8192 f32)
        rsum4[j] = float4{0.f, 0.f, 0.f, 0.f};
    }
}

// ---------------------------------------------------------------------------
// 256x256 8-phase GEMM core (scores_vt). acc[8][4] += A[m,k]*B[n,k].
// Fragment reads hoisted with counted lgkmcnt; q3 reuses B-a regs; counted
// vmcnt(6) at K-tile boundaries. (R10-verified)
// ---------------------------------------------------------------------------
__device__ __forceinline__ void gemm256_core(
    const __hip_bfloat16* __restrict__ A,
    const __hip_bfloat16* __restrict__ B,
    __hip_bfloat16* As, __hip_bfloat16* Bs,
    int m0, int n0, int K, int nkt,
    f32x4 (&acc)[8][4])
{
    const int t   = threadIdx.x;          // 0..511
    const int w   = t >> 6;
    const int l   = t & 63;
    const int lq  = l >> 4;
    const int lm  = l & 15;
    const int wm  = w >> 2;               // M half (0..1)
    const int wn  = w & 3;                // N quarter (0..3)
    const int lm7 = lm & 7;
    const int c0  = (lq ^ lm7) << 3;      // swizzled granule, k-slab 0 (bf16)
    const int c1  = c0 ^ 32;              // k-slab 1

    // staging geometry: thread t covers 16B slots t and 512+t of each region.
    const int rr0   = t >> 3;                         // 0..63
    const int gp8   = (t & 7) << 3;                   // LDS granule (bf16)
    const int g8    = (((t & 7) ^ (rr0 & 7)) << 3);   // pre-swizzled global granule
    const int rowBa = ((rr0 & 32) << 1) | (rr0 & 31); // B-a row-in-half

    const __hip_bfloat16* Aori = A + (size_t)m0 * K;
    const __hip_bfloat16* Bori = B + (size_t)n0 * K;

    auto stage = [&](int reg, int bufT, int kt) {
        const int kc = kt * 64 + g8;
        const __hip_bfloat16* s0;
        __hip_bfloat16* d;
        if (reg == 0) {        // A-lo
            s0 = Aori + (size_t)rr0 * K + kc;
            d  = As + bufT * 16384 + rr0 * 64 + gp8;
        } else if (reg == 2) { // A-hi
            s0 = Aori + (size_t)(64 + rr0) * K + kc;
            d  = As + bufT * 16384 + (64 + rr0) * 64 + gp8;
        } else if (reg == 3) { // B-a
            s0 = Bori + (size_t)rowBa * K + kc;
            d  = Bs + bufT * 16384 + rowBa * 64 + gp8;
        } else {               // B-b
            s0 = Bori + (size_t)(32 + rowBa) * K + kc;
            d  = Bs + bufT * 16384 + (32 + rowBa) * 64 + gp8;
        }
        __builtin_amdgcn_global_load_lds(GPTR(s0), LPTR(d), 16, 0, 0);
        __builtin_amdgcn_global_load_lds(GPTR(s0 + (size_t)128 * K), LPTR(d + 8192), 16, 0, 0);
    };

    // prologue: kt0 {A-lo,B-b,A-hi,B-a} -> buf0; kt1 {A-lo,B-b,A-hi} -> buf1.
    stage(0, 0, 0); stage(1, 0, 0); stage(2, 0, 0); stage(3, 0, 0);
    stage(0, 1, 1); stage(1, 1, 1); stage(2, 1, 1);
    asm volatile("s_waitcnt vmcnt(6)" ::: "memory");   // kt0 complete
    __builtin_amdgcn_s_barrier();

    for (int kt = 0; kt < nkt; ++kt) {
        const int buf = kt & 1;
        const __hip_bfloat16* Ab = As + buf * 16384 + wm * 8192 + lm * 64;
        const __hip_bfloat16* Bb = Bs + buf * 16384 + (wn >> 1) * 8192 + (wn & 1) * 4096 + lm * 64;
        short8 alo[4][2], ahi[4][2], ba[2][2], bb[2][2];

        // ---- K-tile top: issue A-lo(8), B-a(4), B-b(4) reads.
#pragma unroll
        for (int i = 0; i < 4; ++i) {
            alo[i][0] = ds_read128(&Ab[i * 1024 + c0]);
            alo[i][1] = ds_read128(&Ab[i * 1024 + c1]);
        }
#pragma unroll
        for (int j = 0; j < 2; ++j) {
            ba[j][0] = ds_read128(&Bb[j * 1024 + c0]);
            ba[j][1] = ds_read128(&Bb[j * 1024 + c1]);
        }
#pragma unroll
        for (int j = 0; j < 2; ++j) {
            bb[j][0] = ds_read128(&Bb[(2 + j) * 1024 + c0]);
            bb[j][1] = ds_read128(&Bb[(2 + j) * 1024 + c1]);
        }

        // -------- q0: stage B-a(kt+1) -> buf^1 ; MFMA lo x a
        if (kt + 1 < nkt) stage(3, buf ^ 1, kt + 1);
        __builtin_amdgcn_s_barrier();
        asm volatile("s_waitcnt lgkmcnt(4)");
        __builtin_amdgcn_sched_barrier(0);
        __builtin_amdgcn_s_setprio(1);
#pragma unroll
        for (int i = 0; i < 4; ++i)
#pragma unroll
            for (int j = 0; j < 2; ++j) {
                MFMA16(alo[i][0], ba[j][0], acc[i][j]);
                MFMA16(alo[i][1], ba[j][1], acc[i][j]);
            }
        __builtin_amdgcn_s_setprio(0);
        __builtin_amdgcn_s_barrier();

        // -------- q1: stage A-lo(kt+2) ; MFMA lo x b
        if (kt + 2 < nkt) stage(0, buf, kt + 2);
        __builtin_amdgcn_s_barrier();
        asm volatile("s_waitcnt lgkmcnt(0)");
        __builtin_amdgcn_sched_barrier(0);
        __builtin_amdgcn_s_setprio(1);
#pragma unroll
        for (int i = 0; i < 4; ++i)
#pragma unroll
            for (int j = 0; j < 2; ++j) {
                MFMA16(alo[i][0], bb[j][0], acc[i][2 + j]);
                MFMA16(alo[i][1], bb[j][1], acc[i][2 + j]);
            }
        __builtin_amdgcn_s_setprio(0);
        __builtin_amdgcn_s_barrier();

        // -------- q2: read A-hi(8) ; stage B-b(kt+2) ; MFMA hi x b
#pragma unroll
        for (int i = 0; i < 4; ++i) {
            ahi[i][0] = ds_read128(&Ab[(4 + i) * 1024 + c0]);
            ahi[i][1] = ds_read128(&Ab[(4 + i) * 1024 + c1]);
        }
        if (kt + 2 < nkt) stage(1, buf, kt + 2);
        __builtin_amdgcn_s_barrier();
        asm volatile("s_waitcnt lgkmcnt(0)");
        __builtin_amdgcn_sched_barrier(0);
        __builtin_amdgcn_s_setprio(1);
#pragma unroll
        for (int i = 0; i < 4; ++i)
#pragma unroll
            for (int j = 0; j < 2; ++j) {
                MFMA16(ahi[i][0], bb[j][0], acc[4 + i][2 + j]);
                MFMA16(ahi[i][1], bb[j][1], acc[4 + i][2 + j]);
            }
        __builtin_amdgcn_s_setprio(0);
        __builtin_amdgcn_s_barrier();

        // -------- q3: stage A-hi(kt+2) ; MFMA hi x a (B-a regs reused) ; boundary
        if (kt + 2 < nkt) stage(2, buf, kt + 2);
        __builtin_amdgcn_s_setprio(1);
#pragma unroll
        for (int i = 0; i < 4; ++i)
#pragma unroll
            for (int j = 0; j < 2; ++j) {
                MFMA16(ahi[i][0], ba[j][0], acc[4 + i][j]);
                MFMA16(ahi[i][1], ba[j][1], acc[4 + i][j]);
            }
        __builtin_amdgcn_s_setprio(0);
        if (kt + 2 < nkt) {
            asm volatile("s_waitcnt vmcnt(6)" ::: "memory");   // kt+1 ready
        } else if (kt + 1 < nkt) {
            asm volatile("s_waitcnt vmcnt(0)" ::: "memory");   // drain for last
        }
        __builtin_amdgcn_s_barrier();
    }
}

// ---------------------------------------------------------------------------
// scores (144 causal 256x256 tiles: E=exp(scale*QK^T), rowsum atomics) and
// V^T projection (96 tiles) fused in one 240-block dispatch.
// ---------------------------------------------------------------------------
__global__ __launch_bounds__(512, 2) void scores_vt_gemm(
    const __hip_bfloat16* __restrict__ q16,
    const __hip_bfloat16* __restrict__ k16,
    const __hip_bfloat16* __restrict__ x16,
    const __hip_bfloat16* __restrict__ w16,
    __hip_bfloat16* __restrict__ sp16,
    __hip_bfloat16* __restrict__ vt16,
    float* __restrict__ rowsum,
    float scale)
{
    __shared__ __align__(16) __hip_bfloat16 As[2 * 16384];   // 64 KB
    __shared__ __align__(16) __hip_bfloat16 Bs[2 * 16384];   // 64 KB

    const int id = xcd_swz(blockIdx.x, 240);     // 0..239
    const __hip_bfloat16 *A, *B;
    int m0, n0, b;
    const bool is_sc = (id < 144);
    if (is_sc) {
        b = id / 36;
        const int tt = id % 36;           // lower-triangle tile index
        int mi = (int)((sqrtf(8.f * tt + 1.f) - 1.f) * 0.5f);
        while ((mi + 1) * (mi + 2) / 2 <= tt) ++mi;
        while (mi * (mi + 1) / 2 > tt) --mi;
        const int nj = tt - mi * (mi + 1) / 2;
        m0 = mi * 256; n0 = nj * 256;
        A = q16 + (size_t)b * CS * CD;
        B = k16 + (size_t)b * CS * CD;
    } else {
        int r = id - 144;
        b = r / 24; r %= 24;
        m0 = (r >> 3) * 256;              // d-tile
        n0 = (r & 7) * 256;               // s-tile
        A = w16 + (size_t)2 * CD * CD;    // Wv
        B = x16 + (size_t)b * CS * CD;
    }

    f32x4 acc[8][4];
    zero_acc<8>(acc);
    gemm256_core(A, B, As, Bs, m0, n0, CD, CD / 64, acc);

    const int t = threadIdx.x, w = t >> 6, l = t & 63, lq = l >> 4, lm = l & 15;
    const int wm = w >> 2, wn = w & 3;

    if (is_sc) {
        __hip_bfloat16* C = sp16 + (size_t)b * CS * CS;
        float* rs = rowsum + (size_t)b * CS;
#pragma unroll
        for (int i = 0; i < 8; ++i) {
            float psum[4] = {0.f, 0.f, 0.f, 0.f};
#pragma unroll
            for (int j = 0; j < 4; ++j) {
                const int n = n0 + wn * 64 + j * 16 + lm;
#pragma unroll
                for (int r2 = 0; r2 < 4; ++r2) {
                    const int m = m0 + wm * 128 + i * 16 + lq * 4 + r2;
                    float e = (n <= m) ? __expf(acc[i][j][r2] * scale) : 0.f;
                    C[(size_t)m * CS + n] = __float2bfloat16(e);
                    psum[r2] += e;
                }
            }
#pragma unroll
            for (int r2 = 0; r2 < 4; ++r2) {
#pragma unroll
                for (int off = 1; off < 16; off <<= 1)
                    psum[r2] += __shfl_xor(psum[r2], off);
                if (lm == 0) {
                    const int m = m0 + wm * 128 + i * 16 + lq * 4 + r2;
                    atomicAdd(&rs[m], psum[r2]);
                }
            }
        }
    } else {
        __hip_bfloat16* C = vt16 + (size_t)b * CD * CS;
#pragma unroll
        for (int i = 0; i < 8; ++i)
#pragma unroll
            for (int j = 0; j < 4; ++j) {
                const int n = n0 + wn * 64 + j * 16 + lm;
#pragma unroll
                for (int r2 = 0; r2 < 4; ++r2) {
                    const int m = m0 + wm * 128 + i * 16 + lq * 4 + r2;
                    C[(size_t)m * CS + n] = __float2bfloat16(acc[i][j][r2]);
                }
            }
    }
}

// ---------------------------------------------------------------------------
// 2-phase GEMM core (qk): acc[MI][4] += A[m,k]*B[n,k], BM x 128 tile, BK=32
// double-buffered prefetch.
// ---------------------------------------------------------------------------
template <int BM>
__device__ __forceinline__ void gemm_core(
    const __hip_bfloat16* __restrict__ A,
    const __hip_bfloat16* __restrict__ B,
    __hip_bfloat16* As, __hip_bfloat16* Bs,
    int m0, int n0, int K, int kend,
    f32x4 (&acc)[BM / 32][4])
{
    constexpr int AC = BM / 16;
    constexpr int SC = AC + 8;
    constexpr int MI = BM / 32;

    const int t  = threadIdx.x;
    const int w  = t >> 6;
    const int l  = t & 63;
    const int lq = l >> 4;
    const int lm = l & 15;
    const int wm = (w >> 1) * (BM / 2);
    const int wn = (w & 1) * 64;

    const int srow = l >> 2;
    const int scol = (l & 3) * 8;

    auto stage = [&](int buf, int k0) {
#pragma unroll
        for (int ci = 0; ci < SC / 4; ++ci) {
            const int c = ci * 4 + w;
            if (c < AC) {
                __builtin_amdgcn_global_load_lds(
                    GPTR(A + (size_t)(m0 + c * 16 + srow) * K + k0 + scol),
                    LPTR(&As[buf * BM * 32 + c * 512]), 16, 0, 0);
            } else {
                const int c2 = c - AC;
                __builtin_amdgcn_global_load_lds(
                    GPTR(B + (size_t)(n0 + c2 * 16 + srow) * K + k0 + scol),
                    LPTR(&Bs[buf * 128 * 32 + c2 * 512]), 16, 0, 0);
            }
        }
    };

    stage(0, 0);
    asm volatile("s_waitcnt vmcnt(0)" ::: "memory");
    __syncthreads();

    int cur = 0;
    for (int k0 = 0; k0 < kend; k0 += 32) {
        if (k0 + 32 < kend)
            stage(cur ^ 1, k0 + 32);

        short8 af[MI], bf[4];
#pragma unroll
        for (int i = 0; i < MI; ++i)
            af[i] = *(const short8*)&As[cur * BM * 32 + (wm + i * 16 + lm) * 32 + lq * 8];
#pragma unroll
        for (int j = 0; j < 4; ++j)
            bf[j] = *(const short8*)&Bs[cur * 128 * 32 + (wn + j * 16 + lm) * 32 + lq * 8];

#pragma unroll
        for (int i = 0; i < MI; ++i)
#pragma unroll
            for (int j = 0; j < 4; ++j)
                acc[i][j] = __builtin_amdgcn_mfma_f32_16x16x32_bf16(
                    af[i], bf[j], acc[i][j], 0, 0, 0);

        __syncthreads();
        cur ^= 1;
    }
}

// ---------------------------------------------------------------------------
// Q/K projections, 128x128 tiles, 768 blocks (Q: 0..383, K: 384..767).
// Uniform durations -> XCD swizzle is safe here.
// ---------------------------------------------------------------------------
__global__ __launch_bounds__(256) void qk_gemm(
    const __hip_bfloat16* __restrict__ x16,
    const __hip_bfloat16* __restrict__ w16,
    __hip_bfloat16* __restrict__ q16,
    __hip_bfloat16* __restrict__ k16)
{
    __shared__ __align__(16) __hip_bfloat16 As[2 * 128 * 32];   // 16 KB
    __shared__ __align__(16) __hip_bfloat16 Bs[2 * 128 * 32];   // 16 KB

    const int id   = xcd_swz(blockIdx.x, 768);   // 0..767
    const int proj = id / 384;            // 0=Q, 1=K
    const int r    = id % 384;
    const int n0   = (r % 6) * 128;
    const int m0   = (r / 6) * 128;

    f32x4 acc[4][4];
    zero_acc<4>(acc);
    gemm_core<128>(x16, w16 + (size_t)proj * CD * CD, As, Bs, m0, n0, CD, CD, acc);

    __hip_bfloat16* C = proj ? k16 : q16;
    const int t  = threadIdx.x;
    const int w  = t >> 6;
    const int l  = t & 63;
    const int lq = l >> 4;
    const int lm = l & 15;
    const int wm = (w >> 1) * 64;
    const int wn = (w & 1) * 64;
#pragma unroll
    for (int i = 0; i < 4; ++i)
#pragma unroll
        for (int j = 0; j < 4; ++j) {
            const int n = n0 + wn + j * 16 + lm;
#pragma unroll
            for (int r2 = 0; r2 < 4; ++r2) {
                const int m = m0 + wm + i * 16 + lq * 4 + r2;
                C[(size_t)m * CD + n] = __float2bfloat16(acc[i][j][r2]);
            }
        }
}

// ---------------------------------------------------------------------------
// pv core: 64x128 tile, BK=64 (two 32-slabs staged together), double-buffered
// prefetch. Per iteration: 12 load-ops || 16 MFMA, ONE barrier+drain per 64 K.
// LDS: As[2 buf][2 slab][64][32] = 16 KB, Bs[2 buf][2 slab][128][32] = 32 KB.
// kend must be a multiple of 64 (it is: m0+64).
// ---------------------------------------------------------------------------
__device__ __forceinline__ void pv_core(
    const __hip_bfloat16* __restrict__ A,
    const __hip_bfloat16* __restrict__ B,
    __hip_bfloat16* As, __hip_bfloat16* Bs,
    int m0, int n0, int K, int kend,
    f32x4 (&acc)[2][4])
{
    constexpr int AC = 4;           // A chunks (16 rows x 32 cols) per slab
    constexpr int SC = AC + 8;      // 12 chunks per slab

    const int t  = threadIdx.x;
    const int w  = t >> 6;
    const int l  = t & 63;
    const int lq = l >> 4;
    const int lm = l & 15;
    const int wm = (w >> 1) * 32;
    const int wn = (w & 1) * 64;

    const int srow = l >> 2;
    const int scol = (l & 3) * 8;

    // stage both 32-slabs of a 64-K tile into buffer `buf` (24 chunk-ops / 4
    // waves = 6 per wave; chunk id wave-uniform as required).
    auto stage = [&](int buf, int k0) {
#pragma unroll
        for (int ci = 0; ci < 2 * SC / 4; ++ci) {
            const int c    = ci * 4 + w;
            const int slab = (c >= SC) ? 1 : 0;
            const int cc   = c - slab * SC;
            const int kofs = k0 + slab * 32 + scol;
            if (cc < AC) {
                __builtin_amdgcn_global_load_lds(
                    GPTR(A + (size_t)(m0 + cc * 16 + srow) * K + kofs),
                    LPTR(&As[buf * 4096 + slab * 2048 + cc * 512]), 16, 0, 0);
            } else {
                const int c2 = cc - AC;
                __builtin_amdgcn_global_load_lds(
                    GPTR(B + (size_t)(n0 + c2 * 16 + srow) * K + kofs),
                    LPTR(&Bs[buf * 8192 + slab * 4096 + c2 * 512]), 16, 0, 0);
            }
        }
    };

    stage(0, 0);
    asm volatile("s_waitcnt vmcnt(0)" ::: "memory");
    __syncthreads();

    int cur = 0;
    for (int k0 = 0; k0 < kend; k0 += 64) {
        if (k0 + 64 < kend)
            stage(cur ^ 1, k0 + 64);        // prefetch overlaps the MFMAs below

#pragma unroll
        for (int kk = 0; kk < 2; ++kk) {
            short8 af[2], bf[4];
#pragma unroll
            for (int i = 0; i < 2; ++i)
                af[i] = *(const short8*)&As[cur * 4096 + kk * 2048 + (wm + i * 16 + lm) * 32 + lq * 8];
#pragma unroll
            for (int j = 0; j < 4; ++j)
                bf[j] = *(const short8*)&Bs[cur * 8192 + kk * 4096 + (wn + j * 16 + lm) * 32 + lq * 8];
#pragma unroll
            for (int i = 0; i < 2; ++i)
#pragma unroll
                for (int j = 0; j < 4; ++j)
                    acc[i][j] = __builtin_amdgcn_mfma_f32_16x16x32_bf16(
                        af[i], bf[j], acc[i][j], 0, 0, 0);
        }

        // single drain+barrier per 64-K: protects buf reuse AND completes the
        // prefetch issued above (which had the whole compute phase in flight).
        __syncthreads();
        cur ^= 1;
    }
}

// ---------------------------------------------------------------------------
// out[b] = (E[b] @ Vt[b]^T) / rowsum, 64x128 tiles, kend = m0+64,
// heavy-first (LPT) ordering, NO xcd swizzle (R7 lesson).
// ---------------------------------------------------------------------------
__global__ __launch_bounds__(256) void pv_gemm(
    const __hip_bfloat16* __restrict__ sp16,
    const __hip_bfloat16* __restrict__ vt16,
    const float* __restrict__ rowsum,
    float* __restrict__ out)
{
    const int id   = blockIdx.x;        // 0..767
    const int mrev = id / 24;
    int r          = id % 24;
    const int b    = r / 6;
    const int n0   = (r % 6) * 128;
    const int mi   = 31 - mrev;         // heavy (large kend) first
    const int m0   = mi * 64;
    const int kend = m0 + 64;

    __shared__ __align__(16) __hip_bfloat16 As[2 * 4096];   // 16 KB
    __shared__ __align__(16) __hip_bfloat16 Bs[2 * 8192];   // 32 KB

    const __hip_bfloat16* A = sp16 + (size_t)b * CS * CS;
    const __hip_bfloat16* B = vt16 + (size_t)b * CD * CS;
    float* Co = out + (size_t)b * CS * CD;
    const float* rs = rowsum + (size_t)b * CS;

    f32x4 acc[2][4];
    zero_acc<2>(acc);
    pv_core(A, B, As, Bs, m0, n0, CS, kend, acc);

    const int t  = threadIdx.x;
    const int w  = t >> 6;
    const int l  = t & 63;
    const int lq = l >> 4;
    const int lm = l & 15;
    const int wm = (w >> 1) * 32;
    const int wn = (w & 1) * 64;

#pragma unroll
    for (int i = 0; i < 2; ++i) {
        float inv[4];
#pragma unroll
        for (int r2 = 0; r2 < 4; ++r2)
            inv[r2] = 1.0f / rs[m0 + wm + i * 16 + lq * 4 + r2];
#pragma unroll
        for (int j = 0; j < 4; ++j) {
            const int n = n0 + wn + j * 16 + lm;
#pragma unroll
            for (int r2 = 0; r2 < 4; ++r2) {
                const int m = m0 + wm + i * 16 + lq * 4 + r2;
                Co[(size_t)m * CD + n] = acc[i][j][r2] * inv[r2];
            }
        }
    }
}

// ---------------------------------------------------------------------------
// Launch
// ---------------------------------------------------------------------------
extern "C" void kernel_launch(void* const* d_in, const int* in_sizes, int n_in,
                              void* d_out, int out_size, void* d_ws, size_t ws_size,
                              hipStream_t stream)
{
    const float* x  = (const float*)d_in[0];
    const float* Wq = (const float*)d_in[1];
    const float* Wk = (const float*)d_in[2];
    const float* Wv = (const float*)d_in[3];
    float* out = (float*)d_out;

    char* ws = (char*)d_ws;
    size_t off = 0;
    auto alloc = [&](size_t bytes) { char* p = ws + off; off += bytes; return p; };

    __hip_bfloat16* x16  = (__hip_bfloat16*)alloc((size_t)CBS * CD * 2);
    __hip_bfloat16* q16  = (__hip_bfloat16*)alloc((size_t)CBS * CD * 2);
    __hip_bfloat16* k16  = (__hip_bfloat16*)alloc((size_t)CBS * CD * 2);
    __hip_bfloat16* vt16 = (__hip_bfloat16*)alloc((size_t)CBS * CD * 2);   // [B][D][S]
    __hip_bfloat16* sp16 = (__hip_bfloat16*)alloc((size_t)CB * CS * CS * 2);
    __hip_bfloat16* w16  = (__hip_bfloat16*)alloc((size_t)3 * CD * CD * 2);
    float*          rsum = (float*)alloc((size_t)CB * CS * sizeof(float));

    constexpr int NCVT_BLK = (CBS * CD + 3 * CD * CD) / 4 / 256 + 8;
    cvt_all<<<NCVT_BLK, 256, 0, stream>>>(
        (const float4*)x, (const float4*)Wq, (const float4*)Wk, (const float4*)Wv,
        (ushort4*)x16, (ushort4*)w16, (float4*)rsum);

    qk_gemm<<<768, 256, 0, stream>>>(x16, w16, q16, k16);

    scores_vt_gemm<<<240, 512, 0, stream>>>(
        q16, k16, x16, w16, sp16, vt16, rsum, 0.03608439182435161f);

    pv_gemm<<<768, 256, 0, stream>>>(sp16, vt16, rsum, out);
}